// Round 2
// baseline (291.656 us; speedup 1.0000x reference)
//
#include <hip/hip_runtime.h>

#define K 128
#define NB 4096
#define STRIDE 129     // floats per LDS M row; FW column read = 4-way bank aliasing, rowsum conflict-free
#define FW_ITERS 50

__global__ __launch_bounds__(256) void cacis_main(
    const float* __restrict__ scores,
    const float* __restrict__ C,
    const int* __restrict__ targets,
    float* __restrict__ out_partial)
{
    __shared__ float s_lds[K];
    __shared__ float alpha[K];
    __shared__ float grow[K];
    __shared__ float Mf[K * STRIDE];
    __shared__ float red[4][4];

    const int b = blockIdx.x;
    const int tid = threadIdx.x;
    const int w = tid >> 6;
    const int lane = tid & 63;

    if (tid < K) s_lds[tid] = scores[b * K + tid];
    __syncthreads();

    // Thread t owns float4 chunks at element 4*t + 1024*j (j=0..15):
    //   row_j = 8*j + (t>>5), cols [4*(t&31), +4)  -> lane-contiguous (coalesced) global loads
    const float* Cb = C + (size_t)b * (K * K);
    const int cbase = 4 * (tid & 31);
    float4 c[16];
    float sc[4];
    {
        float4 s4 = *reinterpret_cast<const float4*>(&s_lds[cbase]);
        sc[0] = s4.x; sc[1] = s4.y; sc[2] = s4.z; sc[3] = s4.w;
    }

    #pragma unroll
    for (int j = 0; j < 16; ++j)
        c[j] = *reinterpret_cast<const float4*>(Cb + 4 * tid + 1024 * j);

    float sumC = 0.f, trace = 0.f, minv = 1e30f;
    #pragma unroll
    for (int j = 0; j < 16; ++j) {
        const int row = 8 * j + (tid >> 5);
        const float sr = s_lds[row];
        float4 v = c[j];
        sumC += (v.x + v.y) + (v.z + v.w);
        const int d = row - cbase;
        if (d >= 0 && d < 4)
            trace += (d == 0) ? v.x : (d == 1) ? v.y : (d == 2) ? v.z : v.w;
        float t0 = sr + sc[0] + v.x;
        float t1 = sr + sc[1] + v.y;
        float t2 = sr + sc[2] + v.z;
        float t3 = sr + sc[3] + v.w;
        c[j] = make_float4(t0, t1, t2, t3);
        minv = fminf(minv, fminf(fminf(t0, t1), fminf(t2, t3)));
    }

    // block reduce (sumC, trace, minv)
    #pragma unroll
    for (int m = 1; m < 64; m <<= 1) {
        sumC  += __shfl_xor(sumC, m, 64);
        trace += __shfl_xor(trace, m, 64);
        minv   = fminf(minv, __shfl_xor(minv, m, 64));
    }
    if (lane == 0) { red[w][0] = sumC; red[w][1] = trace; red[w][2] = minv; }
    __syncthreads();
    sumC  = (red[0][0] + red[1][0]) + (red[2][0] + red[3][0]);
    trace = (red[0][1] + red[1][1]) + (red[2][1] + red[3][1]);
    minv  = fminf(fminf(red[0][2], red[1][2]), fminf(red[2][2], red[3][2]));

    float eps = (sumC - trace) * (1.0f / (float)(K * (K - 1)));
    eps = fmaxf(eps, 1e-8f);              // EPS_SCALE = 1.0
    const float inv_eps = 1.0f / eps;

    // M = exp((minv - t) * inv_eps): fp32 in registers AND fp32 in LDS
    #pragma unroll
    for (int j = 0; j < 16; ++j) {
        const int row = 8 * j + (tid >> 5);
        float4 v = c[j];
        float m0 = __expf((minv - v.x) * inv_eps);
        float m1 = __expf((minv - v.y) * inv_eps);
        float m2 = __expf((minv - v.z) * inv_eps);
        float m3 = __expf((minv - v.w) * inv_eps);
        c[j] = make_float4(m0, m1, m2, m3);
        float* mp = &Mf[row * STRIDE + cbase];
        mp[0] = m0; mp[1] = m1; mp[2] = m2; mp[3] = m3;
    }
    __syncthreads();

    // initial direction h_0 = rowsum / K  (h = M@alpha; argmin-equivalent to grad = 2*M@alpha)
    if (tid < K) {
        float acc = 0.f;
        const float* rp = &Mf[tid * STRIDE];
        for (int k = 0; k < K; ++k) acc += rp[k];
        grow[tid] = acc * (1.0f / (float)K);
    }
    __syncthreads();

    // Frank-Wolfe: wave 0 only, no barriers in the loop.
    // h' = (1-step)*h + step*M[:,idx]  (exact rank-1 grad update; it=0 has step=1 -> resets FP state)
    if (w == 0) {
        float g0 = grow[2 * lane], g1 = grow[2 * lane + 1];
        float a0 = 1.0f / K, a1 = 1.0f / K;
        #pragma unroll 1
        for (int it = 0; it < FW_ITERS; ++it) {
            float v; int idx;
            if (g0 <= g1) { v = g0; idx = 2 * lane; }     // <= : first-index tie-break
            else          { v = g1; idx = 2 * lane + 1; }
            #pragma unroll
            for (int m = 1; m < 64; m <<= 1) {
                float ov = __shfl_xor(v, m, 64);
                int   oi = __shfl_xor(idx, m, 64);
                if (ov < v || (ov == v && oi < idx)) { v = ov; idx = oi; }
            }
            const float step = 2.0f / (float)(it + 2);
            const float om = 1.0f - step;
            a0 *= om; a1 *= om;
            if (2 * lane == idx)     a0 += step;
            if (2 * lane + 1 == idx) a1 += step;
            const float c0 = Mf[(2 * lane) * STRIDE + idx];
            const float c1 = Mf[(2 * lane + 1) * STRIDE + idx];
            g0 = om * g0 + step * c0;
            g1 = om * g1 + step * c1;
        }
        alpha[2 * lane]     = a0;
        alpha[2 * lane + 1] = a1;
    }
    __syncthreads();

    // val = alpha^T M alpha from fp32 register M
    const float4 ac4 = *reinterpret_cast<const float4*>(&alpha[cbase]);
    float valp = 0.f;
    #pragma unroll
    for (int j = 0; j < 16; ++j) {
        const int row = 8 * j + (tid >> 5);
        const float4 v = c[j];
        const float dot = v.x * ac4.x + v.y * ac4.y + v.z * ac4.z + v.w * ac4.w;
        valp += alpha[row] * dot;
    }
    #pragma unroll
    for (int m = 1; m < 64; m <<= 1) valp += __shfl_xor(valp, m, 64);
    if (lane == 0) red[w][3] = valp;
    __syncthreads();
    if (tid == 0) {
        const float val = (red[0][3] + red[1][3]) + (red[2][3] + red[3][3]);
        // conjugate = -eps*(log(val+1e-12) + shift), shift = -minv/eps  ->  -eps*log(..) + minv
        const float conj = -eps * logf(val + 1e-12f) + minv;
        const int tgt = targets[b];
        out_partial[b] = conj - s_lds[tgt];
    }
}

__global__ __launch_bounds__(256) void cacis_reduce(
    const float* __restrict__ part, float* __restrict__ out)
{
    __shared__ float red[4];
    const int tid = threadIdx.x;
    float acc = 0.f;
    for (int i = tid; i < NB; i += 256) acc += part[i];
    #pragma unroll
    for (int m = 1; m < 64; m <<= 1) acc += __shfl_xor(acc, m, 64);
    if ((tid & 63) == 0) red[tid >> 6] = acc;
    __syncthreads();
    if (tid == 0) out[0] = ((red[0] + red[1]) + (red[2] + red[3])) * (1.0f / (float)NB);
}

extern "C" void kernel_launch(void* const* d_in, const int* in_sizes, int n_in,
                              void* d_out, int out_size, void* d_ws, size_t ws_size,
                              hipStream_t stream) {
    const float* scores  = (const float*)d_in[0];
    const float* C       = (const float*)d_in[1];
    const int*   targets = (const int*)d_in[2];
    float* out  = (float*)d_out;
    float* part = (float*)d_ws;   // NB floats = 16 KB

    cacis_main<<<NB, 256, 0, stream>>>(scores, C, targets, part);
    cacis_reduce<<<1, 256, 0, stream>>>(part, out);
}

// Round 3
// 82.415 us; speedup vs baseline: 3.5389x; 3.5389x over previous
//
#include <hip/hip_runtime.h>
#include <hip/hip_bf16.h>

#define K 128
#define NB 4096
#define STRIDE_H 130   // bf16 elems per LDS M row: word stride 65 == 1 mod 32
#define FW_ITERS 50

// VALU-only min step via DPP (quad_perm / row_ror within 16-lane rows)
template<int CTRL>
__device__ __forceinline__ float dpp_fmin(float v) {
    int iv = __float_as_int(v);
    int s = __builtin_amdgcn_update_dpp(iv, iv, CTRL, 0xF, 0xF, false);
    return fminf(v, __int_as_float(s));
}

// 64-lane min of v, result in all lanes; VALU-only where gfx950 permits
__device__ __forceinline__ float wave_fmin_all(float v) {
    v = dpp_fmin<0xB1>(v);   // quad_perm [1,0,3,2]  (xor 1)
    v = dpp_fmin<0x4E>(v);   // quad_perm [2,3,0,1]  (xor 2)
    v = dpp_fmin<0x124>(v);  // row_ror:4
    v = dpp_fmin<0x128>(v);  // row_ror:8  -> per-16-row min
#if __has_builtin(__builtin_amdgcn_permlane16_swap)
    {
        auto r = __builtin_amdgcn_permlane16_swap(__float_as_int(v), __float_as_int(v), false, false);
        v = fminf(__int_as_float(r[0]), __int_as_float(r[1]));
    }
#else
    v = fminf(v, __shfl_xor(v, 16, 64));
#endif
#if __has_builtin(__builtin_amdgcn_permlane32_swap)
    {
        auto r = __builtin_amdgcn_permlane32_swap(__float_as_int(v), __float_as_int(v), false, false);
        v = fminf(__int_as_float(r[0]), __int_as_float(r[1]));
    }
#else
    v = fminf(v, __shfl_xor(v, 32, 64));
#endif
    return v;
}

__global__ __launch_bounds__(256) void cacis_main(
    const float* __restrict__ scores,
    const float* __restrict__ C,
    const int* __restrict__ targets,
    float* __restrict__ out_partial)
{
    __shared__ float s_lds[K];
    __shared__ float alpha[K];
    __shared__ float grow[K];
    __shared__ float grow2[256];
    __shared__ __hip_bfloat16 Mh[K * STRIDE_H];
    __shared__ float red[4][4];

    const int b = blockIdx.x;
    const int tid = threadIdx.x;
    const int w = tid >> 6;
    const int lane = tid & 63;

    if (tid < K) s_lds[tid] = scores[b * K + tid];
    __syncthreads();

    // Thread t owns float4 chunks at element 4*t + 1024*j (j=0..15):
    //   row_j = 8*j + (t>>5), cols [4*(t&31), +4)  -> lane-contiguous (coalesced)
    const float* Cb = C + (size_t)b * (K * K);
    const int cbase = 4 * (tid & 31);
    float4 c[16];
    float sc[4];
    {
        float4 s4 = *reinterpret_cast<const float4*>(&s_lds[cbase]);
        sc[0] = s4.x; sc[1] = s4.y; sc[2] = s4.z; sc[3] = s4.w;
    }

    #pragma unroll
    for (int j = 0; j < 16; ++j)
        c[j] = *reinterpret_cast<const float4*>(Cb + 4 * tid + 1024 * j);

    float sumC = 0.f, trace = 0.f, minv = 1e30f;
    #pragma unroll
    for (int j = 0; j < 16; ++j) {
        const int row = 8 * j + (tid >> 5);
        const float sr = s_lds[row];
        float4 v = c[j];
        sumC += (v.x + v.y) + (v.z + v.w);
        const int d = row - cbase;
        if (d >= 0 && d < 4)
            trace += (d == 0) ? v.x : (d == 1) ? v.y : (d == 2) ? v.z : v.w;
        float t0 = sr + sc[0] + v.x;
        float t1 = sr + sc[1] + v.y;
        float t2 = sr + sc[2] + v.z;
        float t3 = sr + sc[3] + v.w;
        c[j] = make_float4(t0, t1, t2, t3);
        minv = fminf(minv, fminf(fminf(t0, t1), fminf(t2, t3)));
    }

    // block reduce (sumC, trace, minv)
    #pragma unroll
    for (int m = 1; m < 64; m <<= 1) {
        sumC  += __shfl_xor(sumC, m, 64);
        trace += __shfl_xor(trace, m, 64);
        minv   = fminf(minv, __shfl_xor(minv, m, 64));
    }
    if (lane == 0) { red[w][0] = sumC; red[w][1] = trace; red[w][2] = minv; }
    __syncthreads();
    sumC  = (red[0][0] + red[1][0]) + (red[2][0] + red[3][0]);
    trace = (red[0][1] + red[1][1]) + (red[2][1] + red[3][1]);
    minv  = fminf(fminf(red[0][2], red[1][2]), fminf(red[2][2], red[3][2]));

    float eps = (sumC - trace) * (1.0f / (float)(K * (K - 1)));
    eps = fmaxf(eps, 1e-8f);              // EPS_SCALE = 1.0
    const float inv_eps = 1.0f / eps;

    // M = exp((minv - t) * inv_eps): fp32 in registers, bf16 copy in LDS
    #pragma unroll
    for (int j = 0; j < 16; ++j) {
        const int row = 8 * j + (tid >> 5);
        float4 v = c[j];
        float m0 = __expf((minv - v.x) * inv_eps);
        float m1 = __expf((minv - v.y) * inv_eps);
        float m2 = __expf((minv - v.z) * inv_eps);
        float m3 = __expf((minv - v.w) * inv_eps);
        c[j] = make_float4(m0, m1, m2, m3);
        // two aligned 4B stores of bf16 pairs; 2 lanes/bank -> conflict-free
        __hip_bfloat162* mp = reinterpret_cast<__hip_bfloat162*>(&Mh[row * STRIDE_H + cbase]);
        mp[0] = __hip_bfloat162(__float2bfloat16(m0), __float2bfloat16(m1));
        mp[1] = __hip_bfloat162(__float2bfloat16(m2), __float2bfloat16(m3));
    }
    __syncthreads();

    // h_0 = rowsum / K, parallel over 256 threads (thread: row tid>>1, half tid&1)
    {
        const int row = tid >> 1;
        const int half = tid & 1;
        const __hip_bfloat162* rp =
            reinterpret_cast<const __hip_bfloat162*>(&Mh[row * STRIDE_H + half * 64]);
        float acc = 0.f;
        #pragma unroll
        for (int k2 = 0; k2 < 32; ++k2) {
            float2 f = __bfloat1622float2(rp[k2]);
            acc += f.x + f.y;
        }
        grow2[tid] = acc;
    }
    __syncthreads();
    if (tid < K) grow[tid] = (grow2[2 * tid] + grow2[2 * tid + 1]) * (1.0f / (float)K);
    __syncthreads();

    // Frank-Wolfe: wave 0 only, no barriers in the loop.
    // h' = (1-step)*h + step*M[:,idx]; it=0 has step=1 -> resets FP state exactly
    if (w == 0) {
        float g0 = grow[2 * lane], g1 = grow[2 * lane + 1];
        float a0 = 1.0f / K, a1 = 1.0f / K;
        #pragma unroll 1
        for (int it = 0; it < FW_ITERS; ++it) {
            const float v = wave_fmin_all(fminf(g0, g1));
            // first-index tie-break, scalar-pipe extraction
            unsigned long long b0 = __ballot(g0 == v);
            unsigned long long b1 = __ballot(g1 == v);
            int i0 = b0 ? 2 * (int)__builtin_ctzll(b0)     : 0x7fffffff;
            int i1 = b1 ? 2 * (int)__builtin_ctzll(b1) + 1 : 0x7fffffff;
            const int idx = min(i0, i1);

            const float step = 2.0f / (float)(it + 2);
            const float om = 1.0f - step;
            a0 *= om; a1 *= om;
            if (2 * lane == idx)     a0 += step;
            if (2 * lane + 1 == idx) a1 += step;
            const float c0 = __bfloat162float(Mh[(2 * lane) * STRIDE_H + idx]);
            const float c1 = __bfloat162float(Mh[(2 * lane + 1) * STRIDE_H + idx]);
            g0 = om * g0 + step * c0;
            g1 = om * g1 + step * c1;
        }
        alpha[2 * lane]     = a0;
        alpha[2 * lane + 1] = a1;
    }
    __syncthreads();

    // val = alpha^T M alpha from fp32 register M
    const float4 ac4 = *reinterpret_cast<const float4*>(&alpha[cbase]);
    float valp = 0.f;
    #pragma unroll
    for (int j = 0; j < 16; ++j) {
        const int row = 8 * j + (tid >> 5);
        const float4 v = c[j];
        const float dot = v.x * ac4.x + v.y * ac4.y + v.z * ac4.z + v.w * ac4.w;
        valp += alpha[row] * dot;
    }
    #pragma unroll
    for (int m = 1; m < 64; m <<= 1) valp += __shfl_xor(valp, m, 64);
    if (lane == 0) red[w][3] = valp;
    __syncthreads();
    if (tid == 0) {
        const float val = (red[0][3] + red[1][3]) + (red[2][3] + red[3][3]);
        // conjugate = -eps*(log(val+1e-12) + shift), shift = -minv/eps -> -eps*log(..) + minv
        const float conj = -eps * logf(val + 1e-12f) + minv;
        const int tgt = targets[b];
        out_partial[b] = conj - s_lds[tgt];
    }
}

__global__ __launch_bounds__(256) void cacis_reduce(
    const float* __restrict__ part, float* __restrict__ out)
{
    __shared__ float red[4];
    const int tid = threadIdx.x;
    float acc = 0.f;
    for (int i = tid; i < NB; i += 256) acc += part[i];
    #pragma unroll
    for (int m = 1; m < 64; m <<= 1) acc += __shfl_xor(acc, m, 64);
    if ((tid & 63) == 0) red[tid >> 6] = acc;
    __syncthreads();
    if (tid == 0) out[0] = ((red[0] + red[1]) + (red[2] + red[3])) * (1.0f / (float)NB);
}

extern "C" void kernel_launch(void* const* d_in, const int* in_sizes, int n_in,
                              void* d_out, int out_size, void* d_ws, size_t ws_size,
                              hipStream_t stream) {
    const float* scores  = (const float*)d_in[0];
    const float* C       = (const float*)d_in[1];
    const int*   targets = (const int*)d_in[2];
    float* out  = (float*)d_out;
    float* part = (float*)d_ws;   // NB floats = 16 KB

    cacis_main<<<NB, 256, 0, stream>>>(scores, C, targets, part);
    cacis_reduce<<<1, 256, 0, stream>>>(part, out);
}